// Round 1
// baseline (246.039 us; speedup 1.0000x reference)
//
#include <hip/hip_runtime.h>
#include <math.h>

typedef __attribute__((ext_vector_type(8))) short short8;
typedef __attribute__((ext_vector_type(4))) float float4v;
typedef unsigned int uint;

#define BATCH 8
#define SEQ   4096
#define DIM   768
#define HID   512
#define M_TOK (BATCH * SEQ)   // 32768

// ---------- helpers ----------
static __device__ __forceinline__ short f2bf_rne(float x) {
    unsigned int u = __float_as_uint(x);
    unsigned int r = (u + 0x7FFFu + ((u >> 16) & 1u)) >> 16;   // RNE
    return (short)r;
}
// pack two floats -> 2 bf16 (truncate) in ONE v_perm_b32. lo=bf16(a), hi=bf16(b).
static __device__ __forceinline__ uint pack_bf2(float a, float b) {
    return __builtin_amdgcn_perm(__float_as_uint(b), __float_as_uint(a), 0x07060302u);
}
union FragU { uint u[4]; short8 s; };
// async global->LDS DMA, 16 B per lane; lds dest = uniform base + lane*16,
// global src is PER-LANE (this is how we pre-apply the layout permutation).
static __device__ __forceinline__ void gl2lds16(const void* g, void* l) {
    __builtin_amdgcn_global_load_lds(
        (const __attribute__((address_space(1))) unsigned int*)g,
        (__attribute__((address_space(3))) unsigned int*)l, 16, 0, 0);
}

// ---------- prep: LDS-tiled transpose W1 [DIM][HID] fp32 -> W1T [HID][DIM] bf16 ----------
__global__ __launch_bounds__(256) void prep_kernel(const float* __restrict__ W1,
                                                   short* __restrict__ W1T) {
    __shared__ float t[64][65];
    const int bk = blockIdx.x % 12, bn = blockIdx.x / 12;   // 12 k-tiles x 8 n-tiles
    const int k0 = bk * 64, n0 = bn * 64;
    const int tr = threadIdx.x >> 6, tc = threadIdx.x & 63;
#pragma unroll
    for (int i = 0; i < 16; i++) {
        int k = tr + i * 4;
        t[k][tc] = W1[(size_t)(k0 + k) * HID + n0 + tc];
    }
    __syncthreads();
#pragma unroll
    for (int i = 0; i < 16; i++) {
        int n = tr + i * 4;
        W1T[(size_t)(n0 + n) * DIM + k0 + tc] = f2bf_rne(t[tc][n]);
    }
}

// ---------- MLP: block = 128M x 512N (full N), 8 waves (2 row-groups x 4 col-groups).
// BK=32, 24 steps. Double-buffered LDS (96 KB), T3 minimum-2-phase pipeline:
// issue next-tile DMA BEFORE compute; single __syncthreads per step so the vmcnt(0)
// drain lands after compute has covered the load latency.
// LDS panels stored in FRAGMENT ORDER: every ds_read_b128 is base + lane*16 (linear,
// conflict-free); the permutation is pre-applied to the per-lane global addresses.
#define MLP_BM    128
#define MLP_STEPS 24
#define MLP_ABYTES 16384            // 128 rows x 32 k x 4 B
#define MLP_BBYTES 32768            // 512 rows x 32 k x 2 B
#define MLP_BUF   (MLP_ABYTES + MLP_BBYTES)   // 49152
#define MLP_LDS   (2 * MLP_BUF)               // 98304

__global__ __launch_bounds__(512, 2) void mlp_kernel(const float* __restrict__ A,
                                                     const short* __restrict__ BT,
                                                     const float* __restrict__ b1,
                                                     const float* __restrict__ W2,
                                                     float* __restrict__ logits) {
    extern __shared__ char smem[];
    const int tid = threadIdx.x, wave = tid >> 6, lane = tid & 63;
    const int q = lane >> 4, r = lane & 15;
    const int wr = wave >> 2, wc = wave & 3;     // 2x4 wave grid
    const int m0 = blockIdx.x * MLP_BM;

    // ---- DMA descriptors (per-lane global src, wave-uniform LDS dest) ----
    // A: 16 instrs of 1 KB; wave w issues (group g=w, c=0) and (g=w, c=1).
    // group g = 16 rows; lane l=q*16+r fetches row (m0+g*16+r), floats k= q*8 + c*4 ..+3
    // dest chunk-slot = lane -> LDS addr g*2048 + c*1024 + l*16  (linear)
    const float* aS0 = A + (size_t)(m0 + wave * 16 + r) * DIM + q * 8;
    const float* aS1 = aS0 + 4;
    const int aD0 = wave * 2048, aD1 = wave * 2048 + 1024;
    // B: 32 instrs of 1 KB; wave w issues n-groups h = w*4 .. w*4+3.
    // lane l fetches row (h*16+r), shorts k = q*8..q*8+7 -> dest h*1024 + l*16
    const short* bS[4];
    int bD[4];
#pragma unroll
    for (int j = 0; j < 4; j++) {
        int h = wave * 4 + j;
        bS[j] = BT + (size_t)(h * 16 + r) * DIM + q * 8;
        bD[j] = MLP_ABYTES + h * 1024;
    }

    float4v acc[4][8] = {};

    // prologue: stage step 0 into buf 0
    gl2lds16(aS0, smem + aD0);
    gl2lds16(aS1, smem + aD1);
#pragma unroll
    for (int j = 0; j < 4; j++) gl2lds16(bS[j], smem + bD[j]);
    __syncthreads();   // per-wave vmcnt(0) drain + join: buf0 ready

    for (int p = 0; p < MLP_STEPS; ++p) {
        // issue next tile's DMA first -> overlaps with this step's compute
        if (p + 1 < MLP_STEPS) {
            char* nb = smem + ((p + 1) & 1) * MLP_BUF;
            const int ko = (p + 1) * 32;
            gl2lds16(aS0 + ko, nb + aD0);
            gl2lds16(aS1 + ko, nb + aD1);
#pragma unroll
            for (int j = 0; j < 4; j++) gl2lds16(bS[j] + ko, nb + bD[j]);
        }
        char* base = smem + (p & 1) * MLP_BUF;

        short8 bfr[8];
#pragma unroll
        for (int nf = 0; nf < 8; nf++)
            bfr[nf] = *(const short8*)(base + MLP_ABYTES + (wc * 8 + nf) * 1024 + lane * 16);
#pragma unroll
        for (int mf = 0; mf < 4; mf++) {
            const int g = wr * 4 + mf;
            float4v f0 = *(const float4v*)(base + g * 2048 + lane * 16);          // k=q*8+0..3
            float4v f1 = *(const float4v*)(base + g * 2048 + 1024 + lane * 16);   // k=q*8+4..7
            FragU af;
            af.u[0] = pack_bf2(f0[0], f0[1]);
            af.u[1] = pack_bf2(f0[2], f0[3]);
            af.u[2] = pack_bf2(f1[0], f1[1]);
            af.u[3] = pack_bf2(f1[2], f1[3]);
#pragma unroll
            for (int nf = 0; nf < 8; nf++)
                acc[mf][nf] = __builtin_amdgcn_mfma_f32_16x16x32_bf16(
                    af.s, bfr[nf], acc[mf][nf], 0, 0, 0);
        }
        __syncthreads();   // drains this step's prefetch (landed during compute) + join
    }

    // epilogue: h = relu(acc + b1); per-row partial over this wave's 128 cols
    float b1v[8], w2v[8];
#pragma unroll
    for (int nf = 0; nf < 8; nf++) {
        int gc = wc * 128 + nf * 16 + r;
        b1v[nf] = b1[gc];
        w2v[nf] = W2[gc];
    }
    float* red = (float*)smem;   // [4 colgroups][128 rows] fp32 = 2 KB (reuse buf0 A)
#pragma unroll
    for (int mf = 0; mf < 4; mf++)
#pragma unroll
        for (int v = 0; v < 4; v++) {
            float pp = 0.f;
#pragma unroll
            for (int nf = 0; nf < 8; nf++) {
                float hh = acc[mf][nf][v] + b1v[nf];
                hh = hh > 0.f ? hh : 0.f;
                pp += hh * w2v[nf];
            }
#pragma unroll
            for (int off = 1; off < 16; off <<= 1) pp += __shfl_xor(pp, off, 64);
            if (r == 0) red[wc * 128 + wr * 64 + mf * 16 + q * 4 + v] = pp;
        }
    __syncthreads();
    if (tid < 128) {
        logits[m0 + tid] = red[tid] + red[128 + tid] + red[256 + tid] + red[384 + tid];
    }
}

// ---------- boundary: logits -> hard bits, per-batch scan -> segment starts ----------
__global__ __launch_bounds__(1024) void boundary_kernel(const float* __restrict__ logits,
                                                        const float* __restrict__ b2p,
                                                        const float* __restrict__ noise,
                                                        int* __restrict__ starts,   // [BATCH][SEQ+1]
                                                        int* __restrict__ nseg,     // [BATCH]
                                                        int* __restrict__ nbcount) {// [BATCH]
    const int b = blockIdx.x, tid = threadIdx.x;
    const int base = tid * 4;
    const float b2 = b2p[0];
    int h[4], c = 0;
#pragma unroll
    for (int j = 0; j < 4; j++) {
        int l = base + j;
        float u = noise[b * SEQ + l];
        float lg = logits[b * SEQ + l] + b2 + logf(u) - log1pf(-u);
        h[j] = (lg > 0.f) ? 1 : 0;
        c += h[j];
    }
    const int lane = tid & 63, wid = tid >> 6;
    int inc = c;
    for (int off = 1; off < 64; off <<= 1) {
        int t = __shfl_up(inc, off, 64);
        if (lane >= off) inc += t;
    }
    __shared__ int wtot[16], woff[16], extra[2];
    if (lane == 63) wtot[wid] = inc;
    if (tid == 1023) extra[0] = h[3];
    __syncthreads();
    if (tid == 0) {
        int s = 0;
        for (int i = 0; i < 16; i++) { woff[i] = s; s += wtot[i]; }
        extra[1] = s;
    }
    __syncthreads();
    int run = (inc - c) + woff[wid];       // exclusive prefix of hard bits
#pragma unroll
    for (int j = 0; j < 4; j++) {
        int l = base + j;
        if (h[j]) {
            run++;
            if (l < SEQ - 1) starts[b * (SEQ + 1) + run] = l + 1;
        }
    }
    if (tid == 0) {
        int total = extra[1];
        int ns = total + (extra[0] ? 0 : 1);
        starts[b * (SEQ + 1)] = 0;
        starts[b * (SEQ + 1) + ns] = SEQ;
        nseg[b] = ns;
        nbcount[b] = total;
    }
}

// ---------- pool: 4 waves/block, one wave per slot; 2-way row unroll; NT stores ----------
__global__ __launch_bounds__(256) void pool_kernel(const float* __restrict__ hidden,
                                                   const int* __restrict__ starts,
                                                   const int* __restrict__ nseg,
                                                   float* __restrict__ out) {
    const int wid = threadIdx.x >> 6, lane = threadIdx.x & 63;
    const int s = blockIdx.x * 4 + wid, b = blockIdx.y;
    float* orow = out + (size_t)(b * SEQ + s) * DIM;
    float4v a0 = {0.f, 0.f, 0.f, 0.f}, a1 = a0, a2 = a0;
    const int ns = nseg[b];
    if (s < ns) {
        const int st = starts[b * (SEQ + 1) + s];
        const int en = starts[b * (SEQ + 1) + s + 1];
        float4v c0 = a0, c1 = a0, c2 = a0;
        const float* hbase = hidden + (size_t)(b * SEQ) * DIM;
        int row = st;
        for (; row + 2 <= en; row += 2) {
            const float* h0 = hbase + (size_t)row * DIM;
            const float* h1 = h0 + DIM;
            a0 += *(const float4v*)(h0 + lane * 4);
            a1 += *(const float4v*)(h0 + (lane + 64) * 4);
            a2 += *(const float4v*)(h0 + (lane + 128) * 4);
            c0 += *(const float4v*)(h1 + lane * 4);
            c1 += *(const float4v*)(h1 + (lane + 64) * 4);
            c2 += *(const float4v*)(h1 + (lane + 128) * 4);
        }
        if (row < en) {
            const float* h0 = hbase + (size_t)row * DIM;
            a0 += *(const float4v*)(h0 + lane * 4);
            a1 += *(const float4v*)(h0 + (lane + 64) * 4);
            a2 += *(const float4v*)(h0 + (lane + 128) * 4);
        }
        a0 += c0; a1 += c1; a2 += c2;
        const float invc = 1.f / (float)(en - st);
        a0 *= invc; a1 *= invc; a2 *= invc;
    }
    __builtin_nontemporal_store(a0, (float4v*)(orow + lane * 4));
    __builtin_nontemporal_store(a1, (float4v*)(orow + (lane + 64) * 4));
    __builtin_nontemporal_store(a2, (float4v*)(orow + (lane + 128) * 4));
}

// ---------- finalize: loss / num_boundaries / total_positions ----------
__global__ void finalize_kernel(const int* __restrict__ nbcount, float* __restrict__ tail) {
    int nb = 0;
    for (int i = 0; i < BATCH; i++) nb += nbcount[i];
    float ratio = (float)nb / (float)M_TOK;
    float d = fabsf(ratio - 0.25f) - 0.05f;    // PRIOR + 0.05 = 0.25, margin 0.05
    tail[0] = d > 0.f ? d : 0.f;
    tail[1] = (float)nb;
    tail[2] = (float)M_TOK;
}

// ---------- launch ----------
extern "C" void kernel_launch(void* const* d_in, const int* in_sizes, int n_in,
                              void* d_out, int out_size, void* d_ws, size_t ws_size,
                              hipStream_t stream) {
    const float* hidden = (const float*)d_in[0];
    const float* W1     = (const float*)d_in[1];
    const float* b1     = (const float*)d_in[2];
    const float* W2     = (const float*)d_in[3];
    const float* b2     = (const float*)d_in[4];
    const float* noise  = (const float*)d_in[5];

    char* ws = (char*)d_ws;
    short* W1T    = (short*)(ws);                    // 786432 B
    float* logits = (float*)(ws + 786432);           // 131072 B
    int*   starts = (int*)(ws + 917504);             // 131104 B
    int*   nseg   = (int*)(ws + 917504 + 131104);    // 32 B
    int*   nbcount = nseg + 8;                       // 32 B
    float* out    = (float*)d_out;

    static bool s_mlp_attr = false;
    if (!s_mlp_attr) {
        hipFuncSetAttribute(reinterpret_cast<const void*>(mlp_kernel),
                            hipFuncAttributeMaxDynamicSharedMemorySize, MLP_LDS);
        s_mlp_attr = true;
    }

    prep_kernel<<<96, 256, 0, stream>>>(W1, W1T);
    mlp_kernel<<<M_TOK / MLP_BM, 512, MLP_LDS, stream>>>(hidden, W1T, b1, W2, logits);
    boundary_kernel<<<BATCH, 1024, 0, stream>>>(logits, b2, noise, starts, nseg, nbcount);
    pool_kernel<<<dim3(SEQ / 4, BATCH), 256, 0, stream>>>(hidden, starts, nseg, out);
    finalize_kernel<<<1, 1, 0, stream>>>(nbcount, out + (size_t)M_TOK * DIM);
}

// Round 2
// 233.628 us; speedup vs baseline: 1.0531x; 1.0531x over previous
//
#include <hip/hip_runtime.h>
#include <math.h>

typedef __attribute__((ext_vector_type(8))) short short8;
typedef __attribute__((ext_vector_type(4))) float float4v;
typedef unsigned int uint;

#define BATCH 8
#define SEQ   4096
#define DIM   768
#define HID   512
#define M_TOK (BATCH * SEQ)   // 32768

// ---------- helpers ----------
static __device__ __forceinline__ short f2bf_rne(float x) {
    unsigned int u = __float_as_uint(x);
    unsigned int r = (u + 0x7FFFu + ((u >> 16) & 1u)) >> 16;   // RNE
    return (short)r;
}
// pack two floats -> 2 bf16 (truncate) in ONE v_perm_b32. lo=bf16(a), hi=bf16(b).
static __device__ __forceinline__ uint pack_bf2(float a, float b) {
    return __builtin_amdgcn_perm(__float_as_uint(b), __float_as_uint(a), 0x07060302u);
}
union FragU { uint u[4]; short8 s; };
// async global->LDS DMA, 16 B per lane; lds dest = uniform base + lane*16,
// global src is PER-LANE (this is how we pre-apply the layout permutation).
static __device__ __forceinline__ void gl2lds16(const void* g, void* l) {
    __builtin_amdgcn_global_load_lds(
        (const __attribute__((address_space(1))) unsigned int*)g,
        (__attribute__((address_space(3))) unsigned int*)l, 16, 0, 0);
}

// ---------- prep: LDS-tiled transpose W1 [DIM][HID] fp32 -> W1T [HID][DIM] bf16 ----------
__global__ __launch_bounds__(256) void prep_kernel(const float* __restrict__ W1,
                                                   short* __restrict__ W1T) {
    __shared__ float t[64][65];
    const int bk = blockIdx.x % 12, bn = blockIdx.x / 12;   // 12 k-tiles x 8 n-tiles
    const int k0 = bk * 64, n0 = bn * 64;
    const int tr = threadIdx.x >> 6, tc = threadIdx.x & 63;
#pragma unroll
    for (int i = 0; i < 16; i++) {
        int k = tr + i * 4;
        t[k][tc] = W1[(size_t)(k0 + k) * HID + n0 + tc];
    }
    __syncthreads();
#pragma unroll
    for (int i = 0; i < 16; i++) {
        int n = tr + i * 4;
        W1T[(size_t)(n0 + n) * DIM + k0 + tc] = f2bf_rne(t[tc][n]);
    }
}

// ---------- MLP: block = 128M x 512N (full N), 8 waves (2 row-groups x 4 col-groups).
// BK=32, 24 steps. 3-deep LDS ring (144 KB) with COUNTED vmcnt waits (T3+T4):
// vmcnt never drains to 0 in the main loop -> 2 tiles (96 KB/CU) stay in flight
// across barriers, converting the latency-bound DMA (6.3 B/cyc/CU observed) into
// transfer-bound. Raw s_barrier (no compiler vmcnt(0) drain) + sched_barrier pins.
// LDS panels stored in FRAGMENT ORDER: every ds_read_b128 is base + lane*16 (linear,
// conflict-free); the permutation is pre-applied to the per-lane global addresses.
#define MLP_BM    128
#define MLP_STEPS 24
#define MLP_ABYTES 16384            // 128 rows x 32 k x 4 B
#define MLP_BBYTES 32768            // 512 rows x 32 k x 2 B
#define MLP_BUF   (MLP_ABYTES + MLP_BBYTES)   // 49152
#define MLP_LDS   (3 * MLP_BUF)               // 147456 (3-deep ring)

__global__ __launch_bounds__(512, 2) void mlp_kernel(const float* __restrict__ A,
                                                     const short* __restrict__ BT,
                                                     const float* __restrict__ b1,
                                                     const float* __restrict__ W2,
                                                     float* __restrict__ logits) {
    extern __shared__ char smem[];
    const int tid = threadIdx.x, wave = tid >> 6, lane = tid & 63;
    const int q = lane >> 4, r = lane & 15;
    const int wr = wave >> 2, wc = wave & 3;     // 2x4 wave grid
    const int m0 = blockIdx.x * MLP_BM;

    // ---- DMA descriptors (per-lane global src, wave-uniform LDS dest) ----
    // A: 16 instrs of 1 KB; wave w issues (group g=w, c=0) and (g=w, c=1).
    // group g = 16 rows; lane l=q*16+r fetches row (m0+g*16+r), floats k= q*8 + c*4 ..+3
    // dest chunk-slot = lane -> LDS addr g*2048 + c*1024 + l*16  (linear)
    const float* aS0 = A + (size_t)(m0 + wave * 16 + r) * DIM + q * 8;
    const float* aS1 = aS0 + 4;
    const int aD0 = wave * 2048, aD1 = wave * 2048 + 1024;
    // B: 32 instrs of 1 KB; wave w issues n-groups h = w*4 .. w*4+3.
    // lane l fetches row (h*16+r), shorts k = q*8..q*8+7 -> dest h*1024 + l*16
    const short* bS[4];
    int bD[4];
#pragma unroll
    for (int j = 0; j < 4; j++) {
        int h = wave * 4 + j;
        bS[j] = BT + (size_t)(h * 16 + r) * DIM + q * 8;
        bD[j] = MLP_ABYTES + h * 1024;
    }

    float4v acc[4][8] = {};

    // 6 DMA instrs per wave per tile
    auto stage = [&](int t, char* nb) {
        const int ko = t * 32;
        gl2lds16(aS0 + ko, nb + aD0);
        gl2lds16(aS1 + ko, nb + aD1);
#pragma unroll
        for (int j = 0; j < 4; j++) gl2lds16(bS[j] + ko, nb + bD[j]);
    };
    auto compute = [&](const char* base) {
        short8 bfr[8];
#pragma unroll
        for (int nf = 0; nf < 8; nf++)
            bfr[nf] = *(const short8*)(base + MLP_ABYTES + (wc * 8 + nf) * 1024 + lane * 16);
#pragma unroll
        for (int mf = 0; mf < 4; mf++) {
            const int g = wr * 4 + mf;
            float4v f0 = *(const float4v*)(base + g * 2048 + lane * 16);          // k=q*8+0..3
            float4v f1 = *(const float4v*)(base + g * 2048 + 1024 + lane * 16);   // k=q*8+4..7
            FragU af;
            af.u[0] = pack_bf2(f0[0], f0[1]);
            af.u[1] = pack_bf2(f0[2], f0[3]);
            af.u[2] = pack_bf2(f1[0], f1[1]);
            af.u[3] = pack_bf2(f1[2], f1[3]);
#pragma unroll
            for (int nf = 0; nf < 8; nf++)
                acc[mf][nf] = __builtin_amdgcn_mfma_f32_16x16x32_bf16(
                    af.s, bfr[nf], acc[mf][nf], 0, 0, 0);
        }
    };

    // prologue: fill the ring (18 outstanding DMA instrs / wave)
    stage(0, smem);
    stage(1, smem + MLP_BUF);
    stage(2, smem + 2 * MLP_BUF);

    // steady state: tiles t, t+1, t+2 in flight at loop top (18 outstanding).
    // vmcnt(12) == "my 6 loads for tile t landed"; barrier == everyone's landed.
    for (int t = 0; t <= MLP_STEPS - 4; ++t) {   // t = 0..20
        asm volatile("s_waitcnt vmcnt(12)" ::: "memory");
        __builtin_amdgcn_s_barrier();
        __builtin_amdgcn_sched_barrier(0);
        compute(smem + (t % 3) * MLP_BUF);
        __builtin_amdgcn_sched_barrier(0);
        __builtin_amdgcn_s_barrier();           // all waves done reading buf[t%3]
        stage(t + 3, smem + (t % 3) * MLP_BUF); // overwrite it (lands >= next barrier)
    }
    // tail peel: t = 21 (buf0), 22 (buf1), 23 (buf2); outstanding 18 -> 12 -> 6 -> 0
    asm volatile("s_waitcnt vmcnt(12)" ::: "memory");
    __builtin_amdgcn_s_barrier();
    __builtin_amdgcn_sched_barrier(0);
    compute(smem + ((MLP_STEPS - 3) % 3) * MLP_BUF);
    __builtin_amdgcn_sched_barrier(0);
    asm volatile("s_waitcnt vmcnt(6)" ::: "memory");
    __builtin_amdgcn_s_barrier();
    __builtin_amdgcn_sched_barrier(0);
    compute(smem + ((MLP_STEPS - 2) % 3) * MLP_BUF);
    __builtin_amdgcn_sched_barrier(0);
    asm volatile("s_waitcnt vmcnt(0)" ::: "memory");
    __builtin_amdgcn_s_barrier();
    __builtin_amdgcn_sched_barrier(0);
    compute(smem + ((MLP_STEPS - 1) % 3) * MLP_BUF);

    // epilogue: h = relu(acc + b1); per-row partial over this wave's 128 cols
    float b1v[8], w2v[8];
#pragma unroll
    for (int nf = 0; nf < 8; nf++) {
        int gc = wc * 128 + nf * 16 + r;
        b1v[nf] = b1[gc];
        w2v[nf] = W2[gc];
    }
    // red[] sits in buf0's A region (last read at t=21; all waves past that barrier)
    float* red = (float*)smem;   // [4 colgroups][128 rows] fp32 = 2 KB
#pragma unroll
    for (int mf = 0; mf < 4; mf++)
#pragma unroll
        for (int v = 0; v < 4; v++) {
            float pp = 0.f;
#pragma unroll
            for (int nf = 0; nf < 8; nf++) {
                float hh = acc[mf][nf][v] + b1v[nf];
                hh = hh > 0.f ? hh : 0.f;
                pp += hh * w2v[nf];
            }
#pragma unroll
            for (int off = 1; off < 16; off <<= 1) pp += __shfl_xor(pp, off, 64);
            if (r == 0) red[wc * 128 + wr * 64 + mf * 16 + q * 4 + v] = pp;
        }
    __syncthreads();
    if (tid < 128) {
        logits[m0 + tid] = red[tid] + red[128 + tid] + red[256 + tid] + red[384 + tid];
    }
}

// ---------- boundary: logits -> hard bits, per-batch scan -> segment starts ----------
__global__ __launch_bounds__(1024) void boundary_kernel(const float* __restrict__ logits,
                                                        const float* __restrict__ b2p,
                                                        const float* __restrict__ noise,
                                                        int* __restrict__ starts,   // [BATCH][SEQ+1]
                                                        int* __restrict__ nseg,     // [BATCH]
                                                        int* __restrict__ nbcount) {// [BATCH]
    const int b = blockIdx.x, tid = threadIdx.x;
    const int base = tid * 4;
    const float b2 = b2p[0];
    int h[4], c = 0;
#pragma unroll
    for (int j = 0; j < 4; j++) {
        int l = base + j;
        float u = noise[b * SEQ + l];
        float lg = logits[b * SEQ + l] + b2 + logf(u) - log1pf(-u);
        h[j] = (lg > 0.f) ? 1 : 0;
        c += h[j];
    }
    const int lane = tid & 63, wid = tid >> 6;
    int inc = c;
    for (int off = 1; off < 64; off <<= 1) {
        int t = __shfl_up(inc, off, 64);
        if (lane >= off) inc += t;
    }
    __shared__ int wtot[16], woff[16], extra[2];
    if (lane == 63) wtot[wid] = inc;
    if (tid == 1023) extra[0] = h[3];
    __syncthreads();
    if (tid == 0) {
        int s = 0;
        for (int i = 0; i < 16; i++) { woff[i] = s; s += wtot[i]; }
        extra[1] = s;
    }
    __syncthreads();
    int run = (inc - c) + woff[wid];       // exclusive prefix of hard bits
#pragma unroll
    for (int j = 0; j < 4; j++) {
        int l = base + j;
        if (h[j]) {
            run++;
            if (l < SEQ - 1) starts[b * (SEQ + 1) + run] = l + 1;
        }
    }
    if (tid == 0) {
        int total = extra[1];
        int ns = total + (extra[0] ? 0 : 1);
        starts[b * (SEQ + 1)] = 0;
        starts[b * (SEQ + 1) + ns] = SEQ;
        nseg[b] = ns;
        nbcount[b] = total;
    }
}

// ---------- pool: 4 waves/block, one wave per slot; 2-way row unroll; NT stores ----------
__global__ __launch_bounds__(256) void pool_kernel(const float* __restrict__ hidden,
                                                   const int* __restrict__ starts,
                                                   const int* __restrict__ nseg,
                                                   float* __restrict__ out) {
    const int wid = threadIdx.x >> 6, lane = threadIdx.x & 63;
    const int s = blockIdx.x * 4 + wid, b = blockIdx.y;
    float* orow = out + (size_t)(b * SEQ + s) * DIM;
    float4v a0 = {0.f, 0.f, 0.f, 0.f}, a1 = a0, a2 = a0;
    const int ns = nseg[b];
    if (s < ns) {
        const int st = starts[b * (SEQ + 1) + s];
        const int en = starts[b * (SEQ + 1) + s + 1];
        float4v c0 = a0, c1 = a0, c2 = a0;
        const float* hbase = hidden + (size_t)(b * SEQ) * DIM;
        int row = st;
        for (; row + 2 <= en; row += 2) {
            const float* h0 = hbase + (size_t)row * DIM;
            const float* h1 = h0 + DIM;
            a0 += *(const float4v*)(h0 + lane * 4);
            a1 += *(const float4v*)(h0 + (lane + 64) * 4);
            a2 += *(const float4v*)(h0 + (lane + 128) * 4);
            c0 += *(const float4v*)(h1 + lane * 4);
            c1 += *(const float4v*)(h1 + (lane + 64) * 4);
            c2 += *(const float4v*)(h1 + (lane + 128) * 4);
        }
        if (row < en) {
            const float* h0 = hbase + (size_t)row * DIM;
            a0 += *(const float4v*)(h0 + lane * 4);
            a1 += *(const float4v*)(h0 + (lane + 64) * 4);
            a2 += *(const float4v*)(h0 + (lane + 128) * 4);
        }
        a0 += c0; a1 += c1; a2 += c2;
        const float invc = 1.f / (float)(en - st);
        a0 *= invc; a1 *= invc; a2 *= invc;
    }
    __builtin_nontemporal_store(a0, (float4v*)(orow + lane * 4));
    __builtin_nontemporal_store(a1, (float4v*)(orow + (lane + 64) * 4));
    __builtin_nontemporal_store(a2, (float4v*)(orow + (lane + 128) * 4));
}

// ---------- finalize: loss / num_boundaries / total_positions ----------
__global__ void finalize_kernel(const int* __restrict__ nbcount, float* __restrict__ tail) {
    int nb = 0;
    for (int i = 0; i < BATCH; i++) nb += nbcount[i];
    float ratio = (float)nb / (float)M_TOK;
    float d = fabsf(ratio - 0.25f) - 0.05f;    // PRIOR + 0.05 = 0.25, margin 0.05
    tail[0] = d > 0.f ? d : 0.f;
    tail[1] = (float)nb;
    tail[2] = (float)M_TOK;
}

// ---------- launch ----------
extern "C" void kernel_launch(void* const* d_in, const int* in_sizes, int n_in,
                              void* d_out, int out_size, void* d_ws, size_t ws_size,
                              hipStream_t stream) {
    const float* hidden = (const float*)d_in[0];
    const float* W1     = (const float*)d_in[1];
    const float* b1     = (const float*)d_in[2];
    const float* W2     = (const float*)d_in[3];
    const float* b2     = (const float*)d_in[4];
    const float* noise  = (const float*)d_in[5];

    char* ws = (char*)d_ws;
    short* W1T    = (short*)(ws);                    // 786432 B
    float* logits = (float*)(ws + 786432);           // 131072 B
    int*   starts = (int*)(ws + 917504);             // 131104 B
    int*   nseg   = (int*)(ws + 917504 + 131104);    // 32 B
    int*   nbcount = nseg + 8;                       // 32 B
    float* out    = (float*)d_out;

    static bool s_mlp_attr = false;
    if (!s_mlp_attr) {
        hipFuncSetAttribute(reinterpret_cast<const void*>(mlp_kernel),
                            hipFuncAttributeMaxDynamicSharedMemorySize, MLP_LDS);
        s_mlp_attr = true;
    }

    prep_kernel<<<96, 256, 0, stream>>>(W1, W1T);
    mlp_kernel<<<M_TOK / MLP_BM, 512, MLP_LDS, stream>>>(hidden, W1T, b1, W2, logits);
    boundary_kernel<<<BATCH, 1024, 0, stream>>>(logits, b2, noise, starts, nseg, nbcount);
    pool_kernel<<<dim3(SEQ / 4, BATCH), 256, 0, stream>>>(hidden, starts, nseg, out);
    finalize_kernel<<<1, 1, 0, stream>>>(nbcount, out + (size_t)M_TOK * DIM);
}